// Round 1
// baseline (358.639 us; speedup 1.0000x reference)
//
#include <hip/hip_runtime.h>
#include <hip/hip_bf16.h>
#include <stdint.h>

typedef __bf16 bf16;
typedef __attribute__((ext_vector_type(8))) __bf16 bf16x8;
typedef __attribute__((ext_vector_type(4))) __bf16 bf16x4;
typedef __attribute__((ext_vector_type(4))) float f32x4;

#define S_LEN 2048
#define DMODEL 1024
#define NH 16
#define BATCH 4

// ws layout (bf16 elements):
//   Xc: 3 * 8388608   converted query/key/value
//   Wc: 3 * 1048576   converted wq/wk/wv
//   Pp: 3 * 8388608   projected Q,K,V (bf16)
#define NX 8388608u
#define NW 1048576u
#define WC_OFF (3u * NX)
#define PP_OFF (WC_OFF + 3u * NW)
// total = 53477376 bf16 = ~102 MB of d_ws

static __device__ __forceinline__ void gload_lds16(const void* g, void* l) {
  // direct global->LDS, 16B per lane. LDS dest is wave-uniform-base + lane*16
  // (hardware takes readfirstlane of l); we pass per-thread ptrs that satisfy
  // exactly that relation (lds offset == tid*16B within each wave's chunk).
  __builtin_amdgcn_global_load_lds(
      (const __attribute__((address_space(1))) void*)(g),
      (__attribute__((address_space(3))) void*)(l), 16, 0, 0);
}

// ---------------------------------------------------------------- convert
struct CvtArgs {
  const float* s[6];
  bf16* d[6];
  int n[6];
};

__global__ __launch_bounds__(256) void cvt_f32_bf16(CvtArgs a) {
  const int ai = blockIdx.y;
  const float* __restrict__ s = a.s[ai];
  bf16* __restrict__ d = a.d[ai];
  const int n = a.n[ai];
  const int i = (blockIdx.x * 256 + threadIdx.x) * 8;
  if (i >= n) return;
  const float4* sp = reinterpret_cast<const float4*>(s + i);
  float4 x = sp[0];
  float4 y = sp[1];
  bf16x8 o;
  o[0] = (bf16)x.x; o[1] = (bf16)x.y; o[2] = (bf16)x.z; o[3] = (bf16)x.w;
  o[4] = (bf16)y.x; o[5] = (bf16)y.y; o[6] = (bf16)y.z; o[7] = (bf16)y.w;
  *reinterpret_cast<bf16x8*>(d + i) = o;
}

// ---------------------------------------------------------------- projection
// Y[m][n] = sum_k X[m][k] * W[n][k]   (X: 8192x1024, W: 1024x1024, NT-gemm)
// 128x128 tile, BK=32, 4 waves each owning a 64x64 quadrant (4x4 16x16 frags).
__global__ __launch_bounds__(256, 2) void proj_gemm(const bf16* __restrict__ Xc,
                                                    const bf16* __restrict__ Wc,
                                                    bf16* __restrict__ Yp) {
  const int z = blockIdx.z;
  const bf16* __restrict__ X = Xc + (size_t)z * NX;
  const bf16* __restrict__ W = Wc + (size_t)z * NW;
  bf16* __restrict__ Y = Yp + (size_t)z * NX;

  __shared__ bf16 ldsA[128 * 32];
  __shared__ bf16 ldsB[128 * 32];

  const int tid = threadIdx.x;
  const int lane = tid & 63;
  const int w = tid >> 6;
  const int wr = w >> 1, wc = w & 1;
  const int r16 = lane & 15, g4 = lane >> 4;
  const int m0 = blockIdx.x * 128, n0 = blockIdx.y * 128;

  f32x4 acc[4][4];
#pragma unroll
  for (int mi = 0; mi < 4; mi++)
#pragma unroll
    for (int ni = 0; ni < 4; ni++)
      acc[mi][ni] = (f32x4){0.f, 0.f, 0.f, 0.f};

  const int rowa = tid >> 2;        // 0..63
  const int cola = (tid & 3) * 8;   // 0,8,16,24

  for (int k0 = 0; k0 < DMODEL; k0 += 32) {
    // stage A (128x32) and B (128x32), linear LDS [row][k]
    gload_lds16(X + (size_t)(m0 + rowa) * DMODEL + k0 + cola, &ldsA[tid * 8]);
    gload_lds16(X + (size_t)(m0 + 64 + rowa) * DMODEL + k0 + cola, &ldsA[2048 + tid * 8]);
    gload_lds16(W + (size_t)(n0 + rowa) * DMODEL + k0 + cola, &ldsB[tid * 8]);
    gload_lds16(W + (size_t)(n0 + 64 + rowa) * DMODEL + k0 + cola, &ldsB[2048 + tid * 8]);
    __syncthreads();

    bf16x8 af[4], bfr[4];
#pragma unroll
    for (int mi = 0; mi < 4; mi++)
      af[mi] = *reinterpret_cast<const bf16x8*>(
          &ldsA[(wr * 64 + mi * 16 + r16) * 32 + g4 * 8]);
#pragma unroll
    for (int ni = 0; ni < 4; ni++)
      bfr[ni] = *reinterpret_cast<const bf16x8*>(
          &ldsB[(wc * 64 + ni * 16 + r16) * 32 + g4 * 8]);
#pragma unroll
    for (int mi = 0; mi < 4; mi++)
#pragma unroll
      for (int ni = 0; ni < 4; ni++)
        acc[mi][ni] = __builtin_amdgcn_mfma_f32_16x16x32_bf16(
            af[mi], bfr[ni], acc[mi][ni], 0, 0, 0);
    __syncthreads();
  }

  // epilogue: C/D layout col=lane&15, row=(lane>>4)*4+i  (m89-verified)
#pragma unroll
  for (int mi = 0; mi < 4; mi++)
#pragma unroll
    for (int ni = 0; ni < 4; ni++)
#pragma unroll
      for (int i = 0; i < 4; i++) {
        const int row = m0 + wr * 64 + mi * 16 + g4 * 4 + i;
        const int col = n0 + wc * 64 + ni * 16 + r16;
        Y[(size_t)row * DMODEL + col] = (bf16)acc[mi][ni][i];
      }
}

// ---------------------------------------------------------------- attention
// Flash attention; block = (b, h, 128 q-rows), 4 waves x 32 q-rows.
// Swapped QK^T: S^T = mfma(K_frag, Q_frag) so softmax reduce is over g4 groups
// (2 shfl_xor) and P packs into contiguous 4-elt ds_write_b64.
__global__ __launch_bounds__(256, 2) void attn_kernel(const bf16* __restrict__ Qp,
                                                      const bf16* __restrict__ Kp,
                                                      const bf16* __restrict__ Vp,
                                                      float* __restrict__ Out) {
  // ldsK slot [kv][c']  holds K[kv][c' ^ ((kv&7)*8)]         (read-side deswizzle)
  // ldsVt slot [d][c']  holds V[c' ^ (((d>>3)&7)*8)][d]      (transposed V)
  // ldsP  slot [q][c']  holds P[q][c' ^ ((q&7)*8)]           (per-wave private)
  __shared__ bf16 ldsK[64 * 64];
  __shared__ bf16 ldsVt[64 * 64];
  __shared__ bf16 ldsP[4][32 * 64];

  const int tid = threadIdx.x;
  const int lane = tid & 63;
  const int w = tid >> 6;
  const int r16 = lane & 15, g4 = lane >> 4;
  const int b = blockIdx.z, h = blockIdx.y;
  const int q0 = blockIdx.x * 128 + w * 32;  // this wave's q base

  // Q fragments (B-operand): lane holds Q[q0+qi*16+r16][kk*32+g4*8+j]
  bf16x8 qf[2][2];
#pragma unroll
  for (int qi = 0; qi < 2; qi++)
#pragma unroll
    for (int kk = 0; kk < 2; kk++)
      qf[qi][kk] = *reinterpret_cast<const bf16x8*>(
          Qp + (size_t)(b * S_LEN + q0 + qi * 16 + r16) * DMODEL + h * 64 +
          kk * 32 + g4 * 8);

  f32x4 oacc[2][4];
#pragma unroll
  for (int mi = 0; mi < 2; mi++)
#pragma unroll
    for (int nd = 0; nd < 4; nd++)
      oacc[mi][nd] = (f32x4){0.f, 0.f, 0.f, 0.f};

  float mrun[2] = {-1e30f, -1e30f};
  float lrun[2] = {0.f, 0.f};
  const float inv_scale = 1.0f / 32.0f;  // 1/sqrt(D_MODEL)

  const int srow = tid >> 3;           // 0..31
  const int scol = (tid & 7) * 8;      // 0..56
  const int kswz = ((tid >> 3) & 7) * 8;  // K source pre-swizzle (row&7)
  const int vxor = (tid & 7) * 8;         // V swizzle ((d>>3)&7) for this chunk

  for (int it = 0; it < S_LEN / 64; it++) {
    const int kv0 = it * 64;
    // --- stage K (64x64) via global_load_lds, pre-swizzled source (G21)
    gload_lds16(Kp + (size_t)(b * S_LEN + kv0 + srow) * DMODEL + h * 64 + (scol ^ kswz),
                &ldsK[tid * 8]);
    gload_lds16(Kp + (size_t)(b * S_LEN + kv0 + 32 + srow) * DMODEL + h * 64 + (scol ^ kswz),
                &ldsK[2048 + tid * 8]);
    // --- stage V transposed (scalar writes, XOR-swizzled to ~2-way banks)
#pragma unroll
    for (int half = 0; half < 2; half++) {
      const int rv = srow + half * 32;
      bf16x8 v = *reinterpret_cast<const bf16x8*>(
          Vp + (size_t)(b * S_LEN + kv0 + rv) * DMODEL + h * 64 + scol);
      const int rsw = rv ^ vxor;
#pragma unroll
      for (int j = 0; j < 8; j++) ldsVt[(scol + j) * 64 + rsw] = v[j];
    }
    __syncthreads();

    // --- S^T = K * Q^T : sacc[kvi][qi]; row=kv=kvi*16+g4*4+i, col=q=qi*16+r16
    f32x4 sacc[4][2];
#pragma unroll
    for (int kvi = 0; kvi < 4; kvi++)
#pragma unroll
      for (int qi = 0; qi < 2; qi++) sacc[kvi][qi] = (f32x4){0.f, 0.f, 0.f, 0.f};
#pragma unroll
    for (int kk = 0; kk < 2; kk++) {
      bf16x8 kf[4];
#pragma unroll
      for (int kvi = 0; kvi < 4; kvi++) {
        const int kvr = kvi * 16 + r16;
        const int c = (kk * 32 + g4 * 8) ^ ((kvr & 7) * 8);
        kf[kvi] = *reinterpret_cast<const bf16x8*>(&ldsK[kvr * 64 + c]);
      }
#pragma unroll
      for (int kvi = 0; kvi < 4; kvi++)
#pragma unroll
        for (int qi = 0; qi < 2; qi++)
          sacc[kvi][qi] = __builtin_amdgcn_mfma_f32_16x16x32_bf16(
              kf[kvi], qf[qi][kk], sacc[kvi][qi], 0, 0, 0);
    }

    // --- online softmax (per q column; lane's columns are q=qi*16+r16)
#pragma unroll
    for (int qi = 0; qi < 2; qi++) {
      float tmax = -1e30f;
#pragma unroll
      for (int kvi = 0; kvi < 4; kvi++)
#pragma unroll
        for (int i = 0; i < 4; i++) tmax = fmaxf(tmax, sacc[kvi][qi][i]);
      tmax = fmaxf(tmax, __shfl_xor(tmax, 16, 64));
      tmax = fmaxf(tmax, __shfl_xor(tmax, 32, 64));
      const float mnew = fmaxf(mrun[qi], tmax * inv_scale);
      const float corr = __expf(mrun[qi] - mnew);
      float psum = 0.f;
      const int q = qi * 16 + r16;
#pragma unroll
      for (int kvi = 0; kvi < 4; kvi++) {
        float p0 = __expf(fmaf(sacc[kvi][qi][0], inv_scale, -mnew));
        float p1 = __expf(fmaf(sacc[kvi][qi][1], inv_scale, -mnew));
        float p2 = __expf(fmaf(sacc[kvi][qi][2], inv_scale, -mnew));
        float p3 = __expf(fmaf(sacc[kvi][qi][3], inv_scale, -mnew));
        psum += (p0 + p1) + (p2 + p3);
        const int kvbase = (kvi * 16 + g4 * 4) ^ ((q & 7) * 8);
        bf16x4 pk;
        pk[0] = (bf16)p0; pk[1] = (bf16)p1; pk[2] = (bf16)p2; pk[3] = (bf16)p3;
        *reinterpret_cast<bf16x4*>(&ldsP[w][q * 64 + kvbase]) = pk;
      }
      psum += __shfl_xor(psum, 16, 64);
      psum += __shfl_xor(psum, 32, 64);
      lrun[qi] = lrun[qi] * corr + psum;
      mrun[qi] = mnew;
      // rescale O rows of block qi: O-rows live at q=qi*16+g4*4+i -> fetch corr
      // from the lane that owns that q as a column (lane id = g4*4+i).
#pragma unroll
      for (int i = 0; i < 4; i++) {
        const float corr_r = __shfl(corr, g4 * 4 + i, 64);
#pragma unroll
        for (int nd = 0; nd < 4; nd++) oacc[qi][nd][i] *= corr_r;
      }
    }

    // --- PV: O[q][d] += P[q][kv] * V[kv][d]
#pragma unroll
    for (int kk = 0; kk < 2; kk++) {
      bf16x8 pf[2], vf[4];
#pragma unroll
      for (int mi = 0; mi < 2; mi++) {
        const int q = mi * 16 + r16;
        const int c = (kk * 32 + g4 * 8) ^ ((q & 7) * 8);
        pf[mi] = *reinterpret_cast<const bf16x8*>(&ldsP[w][q * 64 + c]);
      }
#pragma unroll
      for (int nd = 0; nd < 4; nd++) {
        const int d = nd * 16 + r16;
        const int c = (kk * 32 + g4 * 8) ^ (((d >> 3) & 7) * 8);
        vf[nd] = *reinterpret_cast<const bf16x8*>(&ldsVt[d * 64 + c]);
      }
#pragma unroll
      for (int mi = 0; mi < 2; mi++)
#pragma unroll
        for (int nd = 0; nd < 4; nd++)
          oacc[mi][nd] = __builtin_amdgcn_mfma_f32_16x16x32_bf16(
              pf[mi], vf[nd], oacc[mi][nd], 0, 0, 0);
    }
    __syncthreads();
  }

  // epilogue: out[b][q][h*64+d] = O/l ; l redistributed col->row via shfl
#pragma unroll
  for (int mi = 0; mi < 2; mi++)
#pragma unroll
    for (int i = 0; i < 4; i++) {
      const float lr = __shfl(lrun[mi], g4 * 4 + i, 64);
      const float inv_l = 1.0f / lr;
      const int q = q0 + mi * 16 + g4 * 4 + i;
#pragma unroll
      for (int nd = 0; nd < 4; nd++)
        Out[(size_t)(b * S_LEN + q) * DMODEL + h * 64 + nd * 16 + r16] =
            oacc[mi][nd][i] * inv_l;
    }
}

// ---------------------------------------------------------------- launch
extern "C" void kernel_launch(void* const* d_in, const int* in_sizes, int n_in,
                              void* d_out, int out_size, void* d_ws, size_t ws_size,
                              hipStream_t stream) {
  const float* q = (const float*)d_in[0];
  const float* k = (const float*)d_in[1];
  const float* v = (const float*)d_in[2];
  const float* wq = (const float*)d_in[3];
  const float* wk = (const float*)d_in[4];
  const float* wv = (const float*)d_in[5];
  bf16* ws = (bf16*)d_ws;
  bf16* Xc = ws;
  bf16* Wc = ws + WC_OFF;
  bf16* Pp = ws + PP_OFF;
  float* out = (float*)d_out;

  CvtArgs ca;
  ca.s[0] = q;  ca.s[1] = k;  ca.s[2] = v;
  ca.s[3] = wq; ca.s[4] = wk; ca.s[5] = wv;
  ca.d[0] = Xc;          ca.d[1] = Xc + NX;     ca.d[2] = Xc + 2 * NX;
  ca.d[3] = Wc;          ca.d[4] = Wc + NW;     ca.d[5] = Wc + 2 * NW;
  ca.n[0] = ca.n[1] = ca.n[2] = (int)NX;
  ca.n[3] = ca.n[4] = ca.n[5] = (int)NW;
  cvt_f32_bf16<<<dim3(4096, 6, 1), dim3(256), 0, stream>>>(ca);

  proj_gemm<<<dim3(64, 8, 3), dim3(256), 0, stream>>>(Xc, Wc, Pp);

  attn_kernel<<<dim3(S_LEN / 128, NH, BATCH), dim3(256), 0, stream>>>(
      Pp, Pp + NX, Pp + 2 * NX, out);
}

// Round 3
// 353.545 us; speedup vs baseline: 1.0144x; 1.0144x over previous
//
#include <hip/hip_runtime.h>
#include <hip/hip_bf16.h>
#include <stdint.h>

typedef __bf16 bf16;
typedef __attribute__((ext_vector_type(8))) __bf16 bf16x8;
typedef __attribute__((ext_vector_type(4))) __bf16 bf16x4;
typedef __attribute__((ext_vector_type(4))) float f32x4;

#define S_LEN 2048
#define DMODEL 1024
#define NH 16
#define BATCH 4

// ws layout (bf16 elements): Xc 3*NX | Wc 3*NW | Pp 3*NX  (~102 MB)
#define NX 8388608u
#define NW 1048576u
#define WC_OFF (3u * NX)
#define PP_OFF (WC_OFF + 3u * NW)

static __device__ __forceinline__ void gload_lds16(const void* g, void* l) {
  // direct global->LDS DMA, 16B/lane; LDS dest must be wave-uniform base +
  // lane*16 (m104) — our tid*16B offsets satisfy that per wave.
  __builtin_amdgcn_global_load_lds(
      (const __attribute__((address_space(1))) void*)(g),
      (__attribute__((address_space(3))) void*)(l), 16, 0, 0);
}

static __device__ __forceinline__ void wait_lds() {
  // lgkmcnt(0) only — do NOT drain vmcnt (in-flight global stores/DMA).
  // Consumers of the preceding ds_writes are ds_reads (memory ops), so the
  // "memory" clobber orders them (rule #18 hazard is register-only consumers).
  asm volatile("s_waitcnt lgkmcnt(0)" ::: "memory");
}

// ---------------------------------------------------------------- convert
struct CvtArgs {
  const float* s[6];
  bf16* d[6];
  int n[6];
};

__global__ __launch_bounds__(256) void cvt_f32_bf16(CvtArgs a) {
  const int ai = blockIdx.y;
  const float* __restrict__ s = a.s[ai];
  bf16* __restrict__ d = a.d[ai];
  const int n = a.n[ai];
  const int i = (blockIdx.x * 256 + threadIdx.x) * 8;
  if (i >= n) return;
  const float4* sp = reinterpret_cast<const float4*>(s + i);
  float4 x = sp[0];
  float4 y = sp[1];
  bf16x8 o;
  o[0] = (bf16)x.x; o[1] = (bf16)x.y; o[2] = (bf16)x.z; o[3] = (bf16)x.w;
  o[4] = (bf16)y.x; o[5] = (bf16)y.y; o[6] = (bf16)y.z; o[7] = (bf16)y.w;
  *reinterpret_cast<bf16x8*>(d + i) = o;
}

// ---------------------------------------------------------------- projection
// Y[m][n] = sum_k X[m][k]*W[n][k].  128x128 tile, BK=32, 4 waves (2x2 quads).
// 2-phase dbuf: one barrier per K-step, next tile's DMA in flight across it.
__global__ __launch_bounds__(256, 3) void proj_gemm(const bf16* __restrict__ Xc,
                                                    const bf16* __restrict__ Wc,
                                                    bf16* __restrict__ Yp) {
  const int z = blockIdx.z;
  const bf16* __restrict__ X = Xc + (size_t)z * NX;
  const bf16* __restrict__ W = Wc + (size_t)z * NW;
  bf16* __restrict__ Y = Yp + (size_t)z * NX;

  __shared__ bf16 ldsA[2][128 * 32];
  __shared__ bf16 ldsB[2][128 * 32];

  const int tid = threadIdx.x;
  const int lane = tid & 63;
  const int w = tid >> 6;
  const int wr = w >> 1, wc = w & 1;
  const int r16 = lane & 15, g4 = lane >> 4;
  const int m0 = blockIdx.x * 128, n0 = blockIdx.y * 128;

  f32x4 acc[4][4];
#pragma unroll
  for (int mi = 0; mi < 4; mi++)
#pragma unroll
    for (int ni = 0; ni < 4; ni++) acc[mi][ni] = (f32x4){0.f, 0.f, 0.f, 0.f};

  const int rowa = tid >> 2;       // 0..63
  const int cola = (tid & 3) * 8;  // 0,8,16,24

  auto stage = [&](int buf, int k0) {
    gload_lds16(X + (size_t)(m0 + rowa) * DMODEL + k0 + cola, &ldsA[buf][tid * 8]);
    gload_lds16(X + (size_t)(m0 + 64 + rowa) * DMODEL + k0 + cola,
                &ldsA[buf][2048 + tid * 8]);
    gload_lds16(W + (size_t)(n0 + rowa) * DMODEL + k0 + cola, &ldsB[buf][tid * 8]);
    gload_lds16(W + (size_t)(n0 + 64 + rowa) * DMODEL + k0 + cola,
                &ldsB[buf][2048 + tid * 8]);
  };

  stage(0, 0);
  __syncthreads();  // drains prologue DMA (compiler emits vmcnt(0) before barrier)
  int cur = 0;

  for (int k0 = 0; k0 < DMODEL; k0 += 32) {
    if (k0 + 32 < DMODEL) stage(cur ^ 1, k0 + 32);  // in flight across compute

    bf16x8 af[4], bfr[4];
#pragma unroll
    for (int mi = 0; mi < 4; mi++)
      af[mi] = *reinterpret_cast<const bf16x8*>(
          &ldsA[cur][(wr * 64 + mi * 16 + r16) * 32 + g4 * 8]);
#pragma unroll
    for (int ni = 0; ni < 4; ni++)
      bfr[ni] = *reinterpret_cast<const bf16x8*>(
          &ldsB[cur][(wc * 64 + ni * 16 + r16) * 32 + g4 * 8]);
    __builtin_amdgcn_s_setprio(1);
#pragma unroll
    for (int mi = 0; mi < 4; mi++)
#pragma unroll
      for (int ni = 0; ni < 4; ni++)
        acc[mi][ni] = __builtin_amdgcn_mfma_f32_16x16x32_bf16(
            af[mi], bfr[ni], acc[mi][ni], 0, 0, 0);
    __builtin_amdgcn_s_setprio(0);
    __syncthreads();  // releases buf[cur] for next DMA, publishes buf[cur^1]
    cur ^= 1;
  }

  // ---- epilogue: LDS-transpose to coalesced 8B stores. Per-wave-private 4KB
  // carved from ldsA[0..1] (16KB total = 4 waves x 4KB); all DMA drained by the
  // final loop barrier (last-iter prefetch guarded off), so reuse is safe.
  float* shf = reinterpret_cast<float*>(&ldsA[0][0]) + w * 1024;  // 16x64 f32
#pragma unroll
  for (int mi = 0; mi < 4; mi++) {
#pragma unroll
    for (int ni = 0; ni < 4; ni++)
#pragma unroll
      for (int i = 0; i < 4; i++) {
        const int rl = g4 * 4 + i;             // C/D row (m89-verified layout)
        const int cl = ni * 16 + r16;          // C/D col
        shf[rl * 64 + ((cl + 4 * rl) & 63)] = acc[mi][ni][i];  // rot-swizzle
      }
    wait_lds();  // own-wave ds_write -> ds_read ordering
#pragma unroll
    for (int cc = 0; cc < 4; cc++) {
      const int row = g4 + cc * 4;
      const int c0 = r16 * 4;
      const f32x4 vv = *reinterpret_cast<const f32x4*>(
          &shf[row * 64 + ((c0 + 4 * row) & 63)]);
      bf16x4 o;
      o[0] = (bf16)vv[0]; o[1] = (bf16)vv[1]; o[2] = (bf16)vv[2]; o[3] = (bf16)vv[3];
      *reinterpret_cast<bf16x4*>(
          Y + (size_t)(m0 + wr * 64 + mi * 16 + row) * DMODEL + n0 + wc * 64 + c0) = o;
    }
    wait_lds();  // reads done before next mi overwrites the same 4KB
  }
}

// ---------------------------------------------------------------- attention
// Flash attn; block = (b,h,128 q-rows), 4 waves x 32 q-rows, KVBLK=64.
// Swapped QK^T (S^T = mfma(K,Q)); 2-phase dbuf K/Vt, 1 barrier/tile;
// exp2-domain softmax with defer-max (T13); setprio around MFMA (T5).
__global__ __launch_bounds__(256, 3) void attn_kernel(const bf16* __restrict__ Qp,
                                                      const bf16* __restrict__ Kp,
                                                      const bf16* __restrict__ Vp,
                                                      float* __restrict__ Out) {
  // ldsK  slot [kv][c'] holds K[kv][c' ^ ((kv&7)*8)]
  // ldsVt slot [d][c']  holds V[c' ^ swz(d)][d], swz(d)=(((d>>3)^d)&7)*8
  //   (write: 32 banks 2-way=free; b128 read: 8 groups x 8 lanes = floor)
  // ldsP  slot [q][c']  holds P[q][c' ^ ((q&7)*8)]  (per-wave private)
  __shared__ bf16 ldsK[2][64 * 64];
  __shared__ bf16 ldsVt[2][64 * 64];
  __shared__ bf16 ldsP[4][32 * 64];

  const int tid = threadIdx.x;
  const int lane = tid & 63;
  const int w = tid >> 6;
  const int r16 = lane & 15, g4 = lane >> 4;
  const int b = blockIdx.z, h = blockIdx.y;
  const int q0 = blockIdx.x * 128 + w * 32;

  bf16x8 qf[2][2];
#pragma unroll
  for (int qi = 0; qi < 2; qi++)
#pragma unroll
    for (int kk = 0; kk < 2; kk++)
      qf[qi][kk] = *reinterpret_cast<const bf16x8*>(
          Qp + (size_t)(b * S_LEN + q0 + qi * 16 + r16) * DMODEL + h * 64 +
          kk * 32 + g4 * 8);

  f32x4 oacc[2][4];
#pragma unroll
  for (int mi = 0; mi < 2; mi++)
#pragma unroll
    for (int nd = 0; nd < 4; nd++) oacc[mi][nd] = (f32x4){0.f, 0.f, 0.f, 0.f};

  float mrun[2] = {-1e30f, -1e30f};
  float lrun[2] = {0.f, 0.f};
  const float C2 = 0.04508422002778011f;  // log2(e)/32  (exp2-domain softmax)

  const int srow = tid >> 3;              // 0..31
  const int scol = (tid & 7) * 8;         // 0..56
  const int kswz = (srow & 7) * 8;        // K source pre-swizzle (G21)

  auto stageK = [&](int buf, int kv0) {
    gload_lds16(Kp + (size_t)(b * S_LEN + kv0 + srow) * DMODEL + h * 64 + (scol ^ kswz),
                &ldsK[buf][tid * 8]);
    gload_lds16(Kp + (size_t)(b * S_LEN + kv0 + 32 + srow) * DMODEL + h * 64 + (scol ^ kswz),
                &ldsK[buf][2048 + tid * 8]);
  };
  bf16x8 vpre0, vpre1;
  auto loadV = [&](int kv0) {
    vpre0 = *reinterpret_cast<const bf16x8*>(
        Vp + (size_t)(b * S_LEN + kv0 + srow) * DMODEL + h * 64 + scol);
    vpre1 = *reinterpret_cast<const bf16x8*>(
        Vp + (size_t)(b * S_LEN + kv0 + 32 + srow) * DMODEL + h * 64 + scol);
  };
  auto writeV = [&](int buf) {
#pragma unroll
    for (int j = 0; j < 8; j++) {
      const int d = scol + j;
      const int vsw = (((scol >> 3) ^ j) & 7) * 8;
      ldsVt[buf][d * 64 + (srow ^ vsw)] = vpre0[j];
      ldsVt[buf][d * 64 + ((srow + 32) ^ vsw)] = vpre1[j];
    }
  };

  stageK(0, 0);
  loadV(0);
  writeV(0);
  __syncthreads();
  int cur = 0;

  constexpr int NT = S_LEN / 64;
  for (int it = 0; it < NT; it++) {
    const bool pf = (it + 1 < NT);
    if (pf) {
      stageK(cur ^ 1, (it + 1) * 64);  // DMA in flight across this tile
      loadV((it + 1) * 64);            // reg prefetch (T14)
    }

    // --- S^T = K*Q^T
    f32x4 sacc[4][2];
#pragma unroll
    for (int kvi = 0; kvi < 4; kvi++)
#pragma unroll
      for (int qi = 0; qi < 2; qi++) sacc[kvi][qi] = (f32x4){0.f, 0.f, 0.f, 0.f};
#pragma unroll
    for (int kk = 0; kk < 2; kk++) {
      bf16x8 kf[4];
#pragma unroll
      for (int kvi = 0; kvi < 4; kvi++) {
        const int kvr = kvi * 16 + r16;
        const int c = (kk * 32 + g4 * 8) ^ ((r16 & 7) * 8);
        kf[kvi] = *reinterpret_cast<const bf16x8*>(&ldsK[cur][kvr * 64 + c]);
      }
      __builtin_amdgcn_s_setprio(1);
#pragma unroll
      for (int kvi = 0; kvi < 4; kvi++)
#pragma unroll
        for (int qi = 0; qi < 2; qi++)
          sacc[kvi][qi] = __builtin_amdgcn_mfma_f32_16x16x32_bf16(
              kf[kvi], qf[qi][kk], sacc[kvi][qi], 0, 0, 0);
      __builtin_amdgcn_s_setprio(0);
    }

    // --- online softmax in exp2 domain; defer-max (skip rescale if growth<thr)
#pragma unroll
    for (int qi = 0; qi < 2; qi++) {
      float tmax = -1e30f;
#pragma unroll
      for (int kvi = 0; kvi < 4; kvi++)
#pragma unroll
        for (int i = 0; i < 4; i++) tmax = fmaxf(tmax, sacc[kvi][qi][i]);
      tmax = fmaxf(tmax, __shfl_xor(tmax, 16, 64));
      tmax = fmaxf(tmax, __shfl_xor(tmax, 32, 64));
      const float tm2 = tmax * C2;
      const bool resc = !__all(tm2 <= mrun[qi] + 11.0f);
      float mnew = mrun[qi], corr = 1.f;
      if (resc) {
        mnew = fmaxf(mrun[qi], tm2);
        corr = exp2f(mrun[qi] - mnew);
      }
      float psum = 0.f;
      const int q = qi * 16 + r16;
#pragma unroll
      for (int kvi = 0; kvi < 4; kvi++) {
        float p0 = exp2f(fmaf(sacc[kvi][qi][0], C2, -mnew));
        float p1 = exp2f(fmaf(sacc[kvi][qi][1], C2, -mnew));
        float p2 = exp2f(fmaf(sacc[kvi][qi][2], C2, -mnew));
        float p3 = exp2f(fmaf(sacc[kvi][qi][3], C2, -mnew));
        psum += (p0 + p1) + (p2 + p3);
        const int kvbase = (kvi * 16 + g4 * 4) ^ ((q & 7) * 8);
        bf16x4 pk;
        pk[0] = (bf16)p0; pk[1] = (bf16)p1; pk[2] = (bf16)p2; pk[3] = (bf16)p3;
        *reinterpret_cast<bf16x4*>(&ldsP[w][q * 64 + kvbase]) = pk;
      }
      psum += __shfl_xor(psum, 16, 64);
      psum += __shfl_xor(psum, 32, 64);
      if (resc) {
        lrun[qi] = lrun[qi] * corr + psum;
        mrun[qi] = mnew;
#pragma unroll
        for (int i = 0; i < 4; i++) {
          const float corr_r = __shfl(corr, g4 * 4 + i, 64);
#pragma unroll
          for (int nd = 0; nd < 4; nd++) oacc[qi][nd][i] *= corr_r;
        }
      } else {
        lrun[qi] += psum;
      }
    }

    // --- PV
#pragma unroll
    for (int kk = 0; kk < 2; kk++) {
      bf16x8 pfg[2], vf[4];
#pragma unroll
      for (int mi = 0; mi < 2; mi++) {
        const int q = mi * 16 + r16;
        const int c = (kk * 32 + g4 * 8) ^ ((q & 7) * 8);
        pfg[mi] = *reinterpret_cast<const bf16x8*>(&ldsP[w][q * 64 + c]);
      }
#pragma unroll
      for (int nd = 0; nd < 4; nd++) {
        const int d = nd * 16 + r16;
        const int c = (kk * 32 + g4 * 8) ^ ((((d >> 3) ^ d) & 7) * 8);
        vf[nd] = *reinterpret_cast<const bf16x8*>(&ldsVt[cur][d * 64 + c]);
      }
      __builtin_amdgcn_s_setprio(1);
#pragma unroll
      for (int mi = 0; mi < 2; mi++)
#pragma unroll
        for (int nd = 0; nd < 4; nd++)
          oacc[mi][nd] = __builtin_amdgcn_mfma_f32_16x16x32_bf16(
              pfg[mi], vf[nd], oacc[mi][nd], 0, 0, 0);
      __builtin_amdgcn_s_setprio(0);
    }

    if (pf) writeV(cur ^ 1);  // vpre vmcnt-waited here; HBM latency hidden
    __syncthreads();          // publishes next buffers, releases current
    cur ^= 1;
  }

  // epilogue
#pragma unroll
  for (int mi = 0; mi < 2; mi++)
#pragma unroll
    for (int i = 0; i < 4; i++) {
      const float lr = __shfl(lrun[mi], g4 * 4 + i, 64);
      const float inv_l = 1.0f / lr;
      const int q = q0 + mi * 16 + g4 * 4 + i;
#pragma unroll
      for (int nd = 0; nd < 4; nd++)
        Out[(size_t)(b * S_LEN + q) * DMODEL + h * 64 + nd * 16 + r16] =
            oacc[mi][nd][i] * inv_l;
    }
}

// ---------------------------------------------------------------- launch
extern "C" void kernel_launch(void* const* d_in, const int* in_sizes, int n_in,
                              void* d_out, int out_size, void* d_ws, size_t ws_size,
                              hipStream_t stream) {
  const float* q = (const float*)d_in[0];
  const float* k = (const float*)d_in[1];
  const float* v = (const float*)d_in[2];
  const float* wq = (const float*)d_in[3];
  const float* wk = (const float*)d_in[4];
  const float* wv = (const float*)d_in[5];
  bf16* ws = (bf16*)d_ws;
  bf16* Xc = ws;
  bf16* Wc = ws + WC_OFF;
  bf16* Pp = ws + PP_OFF;
  float* out = (float*)d_out;

  CvtArgs ca;
  ca.s[0] = q;  ca.s[1] = k;  ca.s[2] = v;
  ca.s[3] = wq; ca.s[4] = wk; ca.s[5] = wv;
  ca.d[0] = Xc;          ca.d[1] = Xc + NX;     ca.d[2] = Xc + 2 * NX;
  ca.d[3] = Wc;          ca.d[4] = Wc + NW;     ca.d[5] = Wc + 2 * NW;
  ca.n[0] = ca.n[1] = ca.n[2] = (int)NX;
  ca.n[3] = ca.n[4] = ca.n[5] = (int)NW;
  cvt_f32_bf16<<<dim3(4096, 6, 1), dim3(256), 0, stream>>>(ca);

  proj_gemm<<<dim3(64, 8, 3), dim3(256), 0, stream>>>(Xc, Wc, Pp);

  attn_kernel<<<dim3(S_LEN / 128, NH, BATCH), dim3(256), 0, stream>>>(
      Pp, Pp + NX, Pp + 2 * NX, out);
}